// Round 6
// baseline (413.079 us; speedup 1.0000x reference)
//
#include <hip/hip_runtime.h>

#define BB 512
#define SS 168
#define FF 12
#define HH 128
#define UU 256

typedef unsigned short u16;
typedef unsigned int   u32;
typedef _Float16 f16x8 __attribute__((ext_vector_type(8)));
typedef float    f32x4 __attribute__((ext_vector_type(4)));

__device__ __forceinline__ float sigmoidf_(float x){ return __fdividef(1.f, 1.f + __expf(-x)); }
__device__ __forceinline__ float siluf_(float x){ return x * sigmoidf_(x); }
__device__ __forceinline__ float tanhf_(float x){
    float t = __expf(-2.f * fabsf(x));
    float y = __fdividef(1.f - t, 1.f + t);
    return copysignf(y, x);
}
__device__ __forceinline__ u16 f2h_(float v){ return __builtin_bit_cast(u16, (_Float16)v); }
__device__ __forceinline__ f16x8 bc8_(uint4 v){ return __builtin_bit_cast(f16x8, v); }
// A/B fragment slot for element (row/col, k): lane-major, conflict-free b128 reads
__device__ __forceinline__ int aslot_(int row, int k){
    return (k >> 5) * 512 + ((k & 31) >> 3) * 128 + row * 8 + (k & 7);
}

#define MFMA16(a, b, acc) __builtin_amdgcn_mfma_f32_16x16x32_f16((a), (b), (acc), 0, 0, 0)

// ---------------------------------------------------------------------------
// Weight pre-pack, lane-major B-fragments (fp16):
// W0f: 17 tiles x 5 ks (K=160; pad k>=140). tiles 0..15 = Wb0 cols; tile 16 =
//      readout tile: B[k][c] = Wfc[c][k-12] for 12<=k<140, c<3, else 0.
// W1f: 16 tiles x 8 ks (K=256) = Wb1.
// W4f: 24 tiles x 8 ks: tiles 0..7 ff1, 8..15 ff2, 16..23 (Wta+Wtb).
// ---------------------------------------------------------------------------
__global__ void prep_kernel(const float* __restrict__ Wb0, const float* __restrict__ Wb1,
                            const float* __restrict__ Wff1, const float* __restrict__ Wff2,
                            const float* __restrict__ Wta, const float* __restrict__ Wtb,
                            const float* __restrict__ Wfc,
                            u16* __restrict__ W0f, u16* __restrict__ W1f, u16* __restrict__ W4f)
{
    int t = blockIdx.x * blockDim.x + threadIdx.x;
    if (t < 43520) {
        int e = t & 7, c = (t >> 3) & 15, g = (t >> 7) & 3, rest = t >> 9;
        int s = rest % 5, tt = rest / 5;
        int k = s * 32 + g * 8 + e;
        float v;
        if (tt < 16) { int u = tt * 16 + c; v = (k < 140) ? Wb0[u * 140 + k] : 0.f; }
        else         { v = (c < 3 && k >= 12 && k < 140) ? Wfc[c * 128 + (k - 12)] : 0.f; }
        W0f[t] = f2h_(v);
    } else if (t < 43520 + 65536) {
        int t1 = t - 43520;
        int e = t1 & 7, c = (t1 >> 3) & 15, g = (t1 >> 7) & 3, rest = t1 >> 9;
        int s = rest & 7, tt = rest >> 3;
        int u = tt * 16 + c, k = s * 32 + g * 8 + e;
        W1f[t1] = f2h_(Wb1[u * 256 + k]);
    } else if (t < 43520 + 65536 + 98304) {
        int t2 = t - 109056;
        int e = t2 & 7, c = (t2 >> 3) & 15, g = (t2 >> 7) & 3, rest = t2 >> 9;
        int s = rest & 7, tt = rest >> 3;          // 0..23
        int u = (tt & 7) * 16 + c, k = s * 32 + g * 8 + e;
        float v;
        if      (tt < 8)  v = Wff1[u * 256 + k];
        else if (tt < 16) v = Wff2[u * 256 + k];
        else              v = Wta[u * 256 + k] + Wtb[u * 256 + k];
        W4f[t2] = f2h_(v);
    }
}

// ---------------------------------------------------------------------------
// Stage A: seq-mean + centered input, 4-period sff row 0 -> x1.
// ---------------------------------------------------------------------------
__global__ __launch_bounds__(256) void sffA_kernel(
    const float* __restrict__ x,
    const float* __restrict__ c3,  const float* __restrict__ l3,
    const float* __restrict__ c6,  const float* __restrict__ l6,
    const float* __restrict__ c12, const float* __restrict__ l12,
    const float* __restrict__ c24, const float* __restrict__ l24,
    float* __restrict__ meanbuf, float* __restrict__ x1)
{
    int bc = blockIdx.x;
    int b = bc / FF, c = bc % FF;
    __shared__ float v[SS], cv[SS], red[256];
    int tid = threadIdx.x;

    float raw = 0.f;
    if (tid < SS) raw = x[(b * FF + c) * SS + tid];
    red[tid] = raw;
    __syncthreads();
    for (int off = 128; off > 0; off >>= 1) {
        if (tid < off) red[tid] += red[tid + off];
        __syncthreads();
    }
    float mv = red[0] * (1.f / SS);
    if (tid == 0) meanbuf[b * FF + c] = mv;
    if (tid < SS) v[tid] = raw - mv;
    __syncthreads();

    const float* cw[4]  = {c3, c6, c12, c24};
    const float* lwv[4] = {l3, l6, l12, l24};
    const int P[4] = {3, 6, 12, 24};
    float acc = 0.f;
    for (int pi = 0; pi < 4; ++pi) {
        int p = P[pi], pad = p >> 1, k = 1 + 2 * pad, seg = SS / p;
        const float* cwp = cw[pi];
        float cc = 0.f;
        if (tid < SS) {
            cc = v[tid];
            for (int j = 0; j < k; ++j) {
                int t = tid + j - pad;
                if (t >= 0 && t < SS) cc += cwp[j] * v[t];
            }
        }
        __syncthreads();
        if (tid < SS) cv[tid] = cc;
        __syncthreads();
        if (tid < SS) {
            int q = tid / p, ph = tid - q * p;
            const float* lwp = lwv[pi];
            float a = 0.f;
            for (int kk = 0; kk < seg; ++kk) a += lwp[q * seg + kk] * cv[kk * p + ph];
            acc += a;
        }
    }
    if (tid < SS) x1[(b * SS + tid) * FF + c] = 0.25f * acc;
}

// ---------------------------------------------------------------------------
// Stage B: sff rows 1,2 on x1[:,:,:3] -> x2, x3.
// ---------------------------------------------------------------------------
__global__ __launch_bounds__(256) void sffB_kernel(
    const float* __restrict__ x1,
    const float* __restrict__ c3,  const float* __restrict__ l3,
    const float* __restrict__ c6,  const float* __restrict__ l6,
    const float* __restrict__ c12, const float* __restrict__ l12,
    const float* __restrict__ c24, const float* __restrict__ l24,
    float* __restrict__ x2, float* __restrict__ x3)
{
    int bc = blockIdx.x;
    int b = bc / 3, c = bc % 3;
    __shared__ float v[SS], cv[SS];
    int tid = threadIdx.x;
    float raw = 0.f;
    if (tid < SS) raw = x1[(b * SS + tid) * FF + c];
    if (tid < SS) v[tid] = raw;
    __syncthreads();

    const float* cw[4]  = {c3, c6, c12, c24};
    const float* lwv[4] = {l3, l6, l12, l24};
    const int P[4] = {3, 6, 12, 24};
    float acc2 = 0.f, acc3 = 0.f;
    for (int pi = 0; pi < 4; ++pi) {
        int p = P[pi], pad = p >> 1, k = 1 + 2 * pad, seg = SS / p;
        for (int row = 1; row <= 2; ++row) {
            const float* cwp = cw[pi] + row * k;
            float cc = 0.f;
            if (tid < SS) {
                cc = v[tid];
                for (int j = 0; j < k; ++j) {
                    int t = tid + j - pad;
                    if (t >= 0 && t < SS) cc += cwp[j] * v[t];
                }
            }
            __syncthreads();
            if (tid < SS) cv[tid] = cc;
            __syncthreads();
            if (tid < SS) {
                int q = tid / p, ph = tid - q * p;
                const float* lwp = lwv[pi] + row * seg * seg;
                float a = 0.f;
                for (int kk = 0; kk < seg; ++kk) a += lwp[q * seg + kk] * cv[kk * p + ph];
                if (row == 1) acc2 += a; else acc3 += a;
            }
        }
    }
    if (tid < SS) {
        x2[(b * SS + tid) * 3 + c] = 0.25f * acc2;
        x3[(b * SS + tid) * 3 + c] = 0.25f * acc3;
    }
}

// ---------------------------------------------------------------------------
// Persistent-weight MFMA scan: 64 blocks x 512 threads, 8 batch rows/block.
// ALL GEMM weights (W0, W1, W4) persist as B-fragments in registers; only the
// readout tile (5KB) + activations live in LDS. Wave 0 reuses its GEMM1
// A-fragments for the readout MFMA. Zero in-loop global traffic.
// ---------------------------------------------------------------------------
__global__ __launch_bounds__(512, 2) void scan_kernel(
    const float* __restrict__ x1g,
    const uint4* __restrict__ W0f, const uint4* __restrict__ W1f, const uint4* __restrict__ W4f,
    const float* __restrict__ bb0, const float* __restrict__ bb1,
    const float* __restrict__ bff1, const float* __restrict__ bff2,
    const float* __restrict__ bta,  const float* __restrict__ btb,
    const float* __restrict__ bfc,
    float* __restrict__ r1g)
{
    const int b0 = blockIdx.x * 8;
    const int tid = threadIdx.x;
    const int w = tid >> 6, lane = tid & 63;
    const int cl = lane & 15, grp = lane >> 4;

    __shared__ __align__(16) u16 W0ro_s[2560];     // 5KB   readout tile (tile 16)
    __shared__ __align__(16) u16 xh[16128];        // 31.5KB [s][8 rows][12] fp16
    __shared__ __align__(16) u16 zin_s[2560];      // 5KB
    __shared__ __align__(16) u16 z1_s[4096];       // 8KB
    __shared__ __align__(16) u16 z2_s[4096];       // 8KB
    __shared__ __align__(16) float r1s[4032];      // 15.75KB [8][504]
    __shared__ float bfcs[4];

    uint4* W0ro4 = (uint4*)W0ro_s;
    uint4* zin4  = (uint4*)zin_s;
    uint4* z1_4  = (uint4*)z1_s;
    uint4* z2_4  = (uint4*)z2_s;

    // ---- persistent weight fragments -> registers ----
    f16x8 w0a[5], w0b[5];
    f16x8 w1f0[8], w1f1[8], w4a[8], w4b[8], w4c[8];
    #pragma unroll
    for (int s = 0; s < 5; ++s) {
        w0a[s] = bc8_(W0f[((w    ) * 5 + s) * 64 + lane]);
        w0b[s] = bc8_(W0f[((w + 8) * 5 + s) * 64 + lane]);
    }
    #pragma unroll
    for (int s = 0; s < 8; ++s) {
        w1f0[s] = bc8_(W1f[((w     ) * 8 + s) * 64 + lane]);
        w1f1[s] = bc8_(W1f[((w +  8) * 8 + s) * 64 + lane]);
        w4a[s]  = bc8_(W4f[((w     ) * 8 + s) * 64 + lane]);
        w4b[s]  = bc8_(W4f[((w +  8) * 8 + s) * 64 + lane]);
        w4c[s]  = bc8_(W4f[((w + 16) * 8 + s) * 64 + lane]);
    }
    const int u = w * 16 + cl;                     // this thread's unit
    const float bz1a = bb0[u],  bz1b = bb0[128 + u];
    const float bz2a = bb1[u],  bz2b = bb1[128 + u];
    const float bf1r = bff1[u], bf2r = bff2[u];
    const float btsr = bta[u] + btb[u];

    // ---- prologue LDS fills ----
    for (int i = tid; i < 320; i += 512) W0ro4[i] = W0f[5120 + i];   // tile 16
    for (int i = tid; i < 16128; i += 512) {
        int s = i / 96, rem = i - s * 96, r = rem / 12, ii = rem - r * 12;
        xh[i] = f2h_(x1g[((b0 + r) * SS + s) * FF + ii]);
    }
    for (int i = tid; i < 320; i += 512) zin4[i] = make_uint4(0, 0, 0, 0);
    for (int i = tid; i < 512; i += 512) z1_4[i] = make_uint4(0, 0, 0, 0);
    for (int i = tid; i < 512; i += 512) z2_4[i] = make_uint4(0, 0, 0, 0);
    if (tid < 3) bfcs[tid] = bfc[tid];
    __syncthreads();
    if (tid < 96) {                                 // x for s=0
        int r = tid / 12, i = tid % 12;
        int trow = (r >> 1) * 4 + (r & 1);
        zin_s[aslot_(trow, i)] = xh[tid];
    }
    __syncthreads();

    #pragma unroll 1
    for (int s = 0; s < SS; ++s) {
        // ---- Phase A: GEMM1 z1pre = W0 * [x(s); h(s-1)]; wave 0 also does
        //      the readout MFMA for h(s-1) reusing the same A fragments ----
        f32x4 a1a0 = {0.f,0.f,0.f,0.f}, a1a1 = {0.f,0.f,0.f,0.f};
        f32x4 a1b0 = {0.f,0.f,0.f,0.f}, a1b1 = {0.f,0.f,0.f,0.f};
        f32x4 accr = {0.f,0.f,0.f,0.f};
        #pragma unroll
        for (int ks = 0; ks < 5; ++ks) {
            f16x8 av = bc8_(zin4[ks * 64 + lane]);
            if (ks & 1) { a1a1 = MFMA16(av, w0a[ks], a1a1); a1b1 = MFMA16(av, w0b[ks], a1b1); }
            else        { a1a0 = MFMA16(av, w0a[ks], a1a0); a1b0 = MFMA16(av, w0b[ks], a1b0); }
            if (w == 0) accr = MFMA16(av, bc8_(W0ro4[ks * 64 + lane]), accr);
        }
        if (w == 0 && s > 0 && cl < 3) {           // r1 for step s-1
            r1s[(2 * grp    ) * 504 + (s - 1) * 3 + cl] = accr[0] + bfcs[cl];
            r1s[(2 * grp + 1) * 504 + (s - 1) * 3 + cl] = accr[1] + bfcs[cl];
        }

        // silu + write z1 (2 real rows per lane)
        {
            int t0r = grp * 4, t1r = grp * 4 + 1;
            z1_s[aslot_(t0r, u)]       = f2h_(siluf_(a1a0[0] + a1a1[0] + bz1a));
            z1_s[aslot_(t1r, u)]       = f2h_(siluf_(a1a0[1] + a1a1[1] + bz1a));
            z1_s[aslot_(t0r, 128 + u)] = f2h_(siluf_(a1b0[0] + a1b1[0] + bz1b));
            z1_s[aslot_(t1r, 128 + u)] = f2h_(siluf_(a1b0[1] + a1b1[1] + bz1b));
        }
        __syncthreads();

        // ---- Phase B: GEMM2 z2pre = W1 * z1 (B in registers) ----
        f32x4 a2a0 = {0.f,0.f,0.f,0.f}, a2a1 = {0.f,0.f,0.f,0.f};
        f32x4 a2b0 = {0.f,0.f,0.f,0.f}, a2b1 = {0.f,0.f,0.f,0.f};
        #pragma unroll
        for (int ks = 0; ks < 8; ++ks) {
            f16x8 av = bc8_(z1_4[ks * 64 + lane]);
            if (ks & 1) { a2a1 = MFMA16(av, w1f0[ks], a2a1); a2b1 = MFMA16(av, w1f1[ks], a2b1); }
            else        { a2a0 = MFMA16(av, w1f0[ks], a2a0); a2b0 = MFMA16(av, w1f1[ks], a2b0); }
        }
        {
            int t0r = grp * 4, t1r = grp * 4 + 1;
            z2_s[aslot_(t0r, u)]       = f2h_(siluf_(a2a0[0] + a2a1[0] + bz2a));
            z2_s[aslot_(t1r, u)]       = f2h_(siluf_(a2a0[1] + a2a1[1] + bz2a));
            z2_s[aslot_(t0r, 128 + u)] = f2h_(siluf_(a2b0[0] + a2b1[0] + bz2b));
            z2_s[aslot_(t1r, 128 + u)] = f2h_(siluf_(a2b0[1] + a2b1[1] + bz2b));
        }
        __syncthreads();

        // ---- Phase C: GEMM3 [ff1; ff2; tsum]pre = W4 * z2 (B in registers) ----
        f32x4 c3a0 = {0.f,0.f,0.f,0.f}, c3a1 = {0.f,0.f,0.f,0.f};
        f32x4 c3b0 = {0.f,0.f,0.f,0.f}, c3b1 = {0.f,0.f,0.f,0.f};
        f32x4 c3c0 = {0.f,0.f,0.f,0.f}, c3c1 = {0.f,0.f,0.f,0.f};
        #pragma unroll
        for (int ks = 0; ks < 8; ++ks) {
            f16x8 av = bc8_(z2_4[ks * 64 + lane]);
            if (ks & 1) {
                c3a1 = MFMA16(av, w4a[ks], c3a1);
                c3b1 = MFMA16(av, w4b[ks], c3b1);
                c3c1 = MFMA16(av, w4c[ks], c3c1);
            } else {
                c3a0 = MFMA16(av, w4a[ks], c3a0);
                c3b0 = MFMA16(av, w4b[ks], c3b0);
                c3c0 = MFMA16(av, w4c[ks], c3c0);
            }
        }

        // h update (2 real rows per lane, all lanes busy)
        #pragma unroll
        for (int q = 0; q < 2; ++q) {
            float ff1v = tanhf_(c3a0[q] + c3a1[q] + bf1r);
            float ff2v = tanhf_(c3b0[q] + c3b1[q] + bf2r);
            float tv   = sigmoidf_(c3c0[q] + c3c1[q] + btsr);
            float h    = ff1v + tv * (ff2v - ff1v);
            zin_s[aslot_(grp * 4 + q, 12 + u)] = f2h_(h);
        }
        if (tid >= 416 && s + 1 < SS) {            // x(s+1) copy by wave 7
            int idx = tid - 416;
            int r = idx / 12, i = idx % 12;
            int trow = (r >> 1) * 4 + (r & 1);
            zin_s[aslot_(trow, i)] = xh[(s + 1) * 96 + idx];
        }
        __syncthreads();
    }

    // ---- epilogue: readout for s = 167 (h(167) is in zin) ----
    if (w == 0) {
        f32x4 accr = {0.f, 0.f, 0.f, 0.f};
        #pragma unroll
        for (int ks = 0; ks < 5; ++ks)
            accr = MFMA16(bc8_(zin4[ks * 64 + lane]),
                          bc8_(W0ro4[ks * 64 + lane]), accr);
        if (cl < 3) {
            r1s[(2 * grp    ) * 504 + 167 * 3 + cl] = accr[0] + bfcs[cl];
            r1s[(2 * grp + 1) * 504 + 167 * 3 + cl] = accr[1] + bfcs[cl];
        }
    }
    __syncthreads();
    for (int idx = tid; idx < 4032; idx += 512) {
        int r = idx / 504, rem = idx - r * 504;
        r1g[(b0 + r) * 504 + rem] = r1s[r * 504 + rem];
    }
}

// ---------------------------------------------------------------------------
// Final fits einsum (x3 folded in):
// out[b,p,c] = sum_s (r1[b,s,c]+x3[b,s,c]) * Wfits[c,p,s] + mean[b,c] + x2[b,p,c]
// ---------------------------------------------------------------------------
__global__ __launch_bounds__(256) void fits_kernel(
    const float* __restrict__ r1, const float* __restrict__ x3,
    const float* __restrict__ Wfits,
    const float* __restrict__ x2, const float* __restrict__ meanbuf,
    float* __restrict__ out)
{
    int bid = blockIdx.x;
    int bt = bid & 7;
    int rest = bid >> 3;
    int c = rest % 3;
    int pt = rest / 3;
    int b0 = bt * 64, p0 = pt * 28;
    __shared__ float rT[168][65];
    __shared__ float wT[28][168];
    int t = threadIdx.x;
    for (int idx = t; idx < 64 * 168; idx += 256) {
        int b = idx / 168, s = idx - b * 168;
        int gi = ((b0 + b) * 168 + s) * 3 + c;
        rT[s][b] = r1[gi] + x3[gi];
    }
    for (int idx = t; idx < 28 * 168; idx += 256) {
        int p = idx / 168, s = idx - p * 168;
        wT[p][s] = Wfits[(c * 168 + p0 + p) * 168 + s];
    }
    __syncthreads();
    int b = t & 63, pq = t >> 6;
    float acc[7] = {0, 0, 0, 0, 0, 0, 0};
    for (int s = 0; s < 168; ++s) {
        float v = rT[s][b];
        #pragma unroll
        for (int j = 0; j < 7; ++j) acc[j] += v * wT[pq * 7 + j][s];
    }
    float mb = meanbuf[(b0 + b) * 12 + c];
    #pragma unroll
    for (int j = 0; j < 7; ++j) {
        int p = p0 + pq * 7 + j;
        int gi = ((b0 + b) * 168 + p) * 3 + c;
        out[gi] = acc[j] + mb + x2[gi];
    }
}

extern "C" void kernel_launch(void* const* d_in, const int* in_sizes, int n_in,
                              void* d_out, int out_size, void* d_ws, size_t ws_size,
                              hipStream_t stream) {
    const float* x    = (const float*)d_in[0];
    const float* c3   = (const float*)d_in[1];
    const float* l3   = (const float*)d_in[2];
    const float* c6   = (const float*)d_in[3];
    const float* l6   = (const float*)d_in[4];
    const float* c12  = (const float*)d_in[5];
    const float* l12  = (const float*)d_in[6];
    const float* c24  = (const float*)d_in[7];
    const float* l24  = (const float*)d_in[8];
    const float* Wb0  = (const float*)d_in[9];
    const float* bb0  = (const float*)d_in[10];
    const float* Wb1  = (const float*)d_in[11];
    const float* bb1  = (const float*)d_in[12];
    const float* Wff1 = (const float*)d_in[13];
    const float* bff1 = (const float*)d_in[14];
    const float* Wff2 = (const float*)d_in[15];
    const float* bff2 = (const float*)d_in[16];
    const float* Wta  = (const float*)d_in[17];
    const float* bta  = (const float*)d_in[18];
    const float* Wtb  = (const float*)d_in[19];
    const float* btb  = (const float*)d_in[20];
    const float* Wfc  = (const float*)d_in[21];
    const float* bfc  = (const float*)d_in[22];
    const float* Wfits= (const float*)d_in[23];

    float* ws      = (float*)d_ws;
    float* meanbuf = ws;                    // 6144
    float* x1      = meanbuf + 6144;        // 1032192
    float* x2      = x1 + 1032192;          // 258048
    float* x3      = x2 + 258048;           // 258048
    float* r1      = x3 + 258048;           // 258048
    u16*   W0f     = (u16*)(r1 + 258048);   // 43520 u16 (16B aligned)
    u16*   W1f     = W0f + 43520;           // 65536 u16
    u16*   W4f     = W1f + 65536;           // 98304 u16
    float* out     = (float*)d_out;

    prep_kernel<<<(207360 + 255) / 256, 256, 0, stream>>>(Wb0, Wb1, Wff1, Wff2, Wta, Wtb, Wfc, W0f, W1f, W4f);
    sffA_kernel<<<BB * FF, 256, 0, stream>>>(x, c3, l3, c6, l6, c12, l12, c24, l24, meanbuf, x1);
    sffB_kernel<<<BB * 3, 256, 0, stream>>>(x1, c3, l3, c6, l6, c12, l12, c24, l24, x2, x3);
    scan_kernel<<<BB / 8, 512, 0, stream>>>(x1,
                                            (const uint4*)W0f, (const uint4*)W1f, (const uint4*)W4f,
                                            bb0, bb1, bff1, bff2, bta, btb, bfc, r1);
    fits_kernel<<<144, 256, 0, stream>>>(r1, x3, Wfits, x2, meanbuf, out);
}

// Round 7
// 342.172 us; speedup vs baseline: 1.2072x; 1.2072x over previous
//
#include <hip/hip_runtime.h>

#define BB 512
#define SS 168
#define FF 12
#define HH 128
#define UU 256

typedef unsigned short u16;
typedef unsigned int   u32;
typedef _Float16 f16x8 __attribute__((ext_vector_type(8)));
typedef float    f32x4 __attribute__((ext_vector_type(4)));

__device__ __forceinline__ float sigmoidf_(float x){ return __fdividef(1.f, 1.f + __expf(-x)); }
__device__ __forceinline__ float siluf_(float x){ return x * sigmoidf_(x); }
__device__ __forceinline__ float tanhf_(float x){
    float t = __expf(-2.f * fabsf(x));
    float y = __fdividef(1.f - t, 1.f + t);
    return copysignf(y, x);
}
__device__ __forceinline__ u16 f2h_(float v){ return __builtin_bit_cast(u16, (_Float16)v); }
__device__ __forceinline__ f16x8 bc8_(uint4 v){ return __builtin_bit_cast(f16x8, v); }
// A/B fragment slot for element (row/col, k): lane-major, conflict-free b128 reads
__device__ __forceinline__ int aslot_(int row, int k){
    return (k >> 5) * 512 + ((k & 31) >> 3) * 128 + row * 8 + (k & 7);
}

#define MFMA16(a, b, acc) __builtin_amdgcn_mfma_f32_16x16x32_f16((a), (b), (acc), 0, 0, 0)

#define PREP_BLOCKS 810           // ceil(207360 / 256)
#define SFFA_BLOCKS (BB * FF)     // 6144

// ---------------------------------------------------------------------------
// Fused front-end kernel.
// Blocks [0, PREP_BLOCKS): weight pre-pack into lane-major MFMA B-fragments.
//   W0f: 17 tiles x 5 ks (K=160; pad k>=140); tile 16 = readout (Wfc).
//   W1f: 16 tiles x 8 ks; W4f: 24 tiles x 8 ks [ff1; ff2; Wta+Wtb].
// Blocks [PREP_BLOCKS, ..): per-(b,c) sff stage A (row 0 -> x1); blocks with
//   c<3 continue with rows 1,2 on their own x1 series -> x2, x3.
// ---------------------------------------------------------------------------
__global__ __launch_bounds__(256) void front_kernel(
    const float* __restrict__ x,
    const float* __restrict__ c3,  const float* __restrict__ l3,
    const float* __restrict__ c6,  const float* __restrict__ l6,
    const float* __restrict__ c12, const float* __restrict__ l12,
    const float* __restrict__ c24, const float* __restrict__ l24,
    const float* __restrict__ Wb0, const float* __restrict__ Wb1,
    const float* __restrict__ Wff1, const float* __restrict__ Wff2,
    const float* __restrict__ Wta, const float* __restrict__ Wtb,
    const float* __restrict__ Wfc,
    u16* __restrict__ W0f, u16* __restrict__ W1f, u16* __restrict__ W4f,
    float* __restrict__ meanbuf, float* __restrict__ x1,
    float* __restrict__ x2, float* __restrict__ x3)
{
    if (blockIdx.x < PREP_BLOCKS) {
        int t = blockIdx.x * 256 + threadIdx.x;
        if (t < 43520) {
            int e = t & 7, c = (t >> 3) & 15, g = (t >> 7) & 3, rest = t >> 9;
            int s = rest % 5, tt = rest / 5;
            int k = s * 32 + g * 8 + e;
            float v;
            if (tt < 16) { int u = tt * 16 + c; v = (k < 140) ? Wb0[u * 140 + k] : 0.f; }
            else         { v = (c < 3 && k >= 12 && k < 140) ? Wfc[c * 128 + (k - 12)] : 0.f; }
            W0f[t] = f2h_(v);
        } else if (t < 43520 + 65536) {
            int t1 = t - 43520;
            int e = t1 & 7, c = (t1 >> 3) & 15, g = (t1 >> 7) & 3, rest = t1 >> 9;
            int s = rest & 7, tt = rest >> 3;
            int u = tt * 16 + c, k = s * 32 + g * 8 + e;
            W1f[t1] = f2h_(Wb1[u * 256 + k]);
        } else if (t < 43520 + 65536 + 98304) {
            int t2 = t - 109056;
            int e = t2 & 7, c = (t2 >> 3) & 15, g = (t2 >> 7) & 3, rest = t2 >> 9;
            int s = rest & 7, tt = rest >> 3;          // 0..23
            int u = (tt & 7) * 16 + c, k = s * 32 + g * 8 + e;
            float v;
            if      (tt < 8)  v = Wff1[u * 256 + k];
            else if (tt < 16) v = Wff2[u * 256 + k];
            else              v = Wta[u * 256 + k] + Wtb[u * 256 + k];
            W4f[t2] = f2h_(v);
        }
        return;
    }

    int bc = blockIdx.x - PREP_BLOCKS;
    int b = bc / FF, c = bc % FF;
    __shared__ float v[SS], cv[SS], red[256];
    int tid = threadIdx.x;

    float raw = 0.f;
    if (tid < SS) raw = x[(b * FF + c) * SS + tid];
    red[tid] = raw;
    __syncthreads();
    for (int off = 128; off > 0; off >>= 1) {
        if (tid < off) red[tid] += red[tid + off];
        __syncthreads();
    }
    float mv = red[0] * (1.f / SS);
    if (tid == 0) meanbuf[b * FF + c] = mv;
    if (tid < SS) v[tid] = raw - mv;
    __syncthreads();

    const float* cw[4]  = {c3, c6, c12, c24};
    const float* lwv[4] = {l3, l6, l12, l24};
    const int P[4] = {3, 6, 12, 24};
    float acc = 0.f;
    for (int pi = 0; pi < 4; ++pi) {
        int p = P[pi], pad = p >> 1, k = 1 + 2 * pad, seg = SS / p;
        const float* cwp = cw[pi];
        float cc = 0.f;
        if (tid < SS) {
            cc = v[tid];
            for (int j = 0; j < k; ++j) {
                int t = tid + j - pad;
                if (t >= 0 && t < SS) cc += cwp[j] * v[t];
            }
        }
        __syncthreads();
        if (tid < SS) cv[tid] = cc;
        __syncthreads();
        if (tid < SS) {
            int q = tid / p, ph = tid - q * p;
            const float* lwp = lwv[pi];
            float a = 0.f;
            for (int kk = 0; kk < seg; ++kk) a += lwp[q * seg + kk] * cv[kk * p + ph];
            acc += a;
        }
    }
    float x1v = 0.25f * acc;
    if (tid < SS) x1[(b * SS + tid) * FF + c] = x1v;
    if (c >= 3) return;

    // ---- stage B on this (b, c<3) series: rows 1,2 -> x2, x3 ----
    __syncthreads();
    if (tid < SS) v[tid] = x1v;
    __syncthreads();
    float acc2 = 0.f, acc3 = 0.f;
    for (int pi = 0; pi < 4; ++pi) {
        int p = P[pi], pad = p >> 1, k = 1 + 2 * pad, seg = SS / p;
        for (int row = 1; row <= 2; ++row) {
            const float* cwp = cw[pi] + row * k;
            float cc = 0.f;
            if (tid < SS) {
                cc = v[tid];
                for (int j = 0; j < k; ++j) {
                    int t = tid + j - pad;
                    if (t >= 0 && t < SS) cc += cwp[j] * v[t];
                }
            }
            __syncthreads();
            if (tid < SS) cv[tid] = cc;
            __syncthreads();
            if (tid < SS) {
                int q = tid / p, ph = tid - q * p;
                const float* lwp = lwv[pi] + row * seg * seg;
                float a = 0.f;
                for (int kk = 0; kk < seg; ++kk) a += lwp[q * seg + kk] * cv[kk * p + ph];
                if (row == 1) acc2 += a; else acc3 += a;
            }
        }
    }
    if (tid < SS) {
        x2[(b * SS + tid) * 3 + c] = 0.25f * acc2;
        x3[(b * SS + tid) * 3 + c] = 0.25f * acc3;
    }
}

// ---------------------------------------------------------------------------
// Persistent-weight MFMA scan: 128 blocks x 512 threads, 4 batch rows/block.
// Batch row r -> tile row 4r: each lane's acc[0] is a real row -> exactly one
// activation slot per lane per output tile (half the per-wave VALU issue of
// the 8-row variant). All weights in registers; readout via extra MFMA tile.
// ---------------------------------------------------------------------------
__global__ __launch_bounds__(512, 2) void scan_kernel(
    const float* __restrict__ x1g,
    const uint4* __restrict__ W0f, const uint4* __restrict__ W1f, const uint4* __restrict__ W4f,
    const float* __restrict__ bb0, const float* __restrict__ bb1,
    const float* __restrict__ bff1, const float* __restrict__ bff2,
    const float* __restrict__ bta,  const float* __restrict__ btb,
    const float* __restrict__ bfc,
    float* __restrict__ r1g)
{
    const int b0 = blockIdx.x * 4;
    const int tid = threadIdx.x;
    const int w = tid >> 6, lane = tid & 63;
    const int cl = lane & 15, grp = lane >> 4;

    __shared__ __align__(16) u16 W0ro_s[2560];     // 5KB   readout tile (tile 16)
    __shared__ __align__(16) u16 xh[8064];         // 15.75KB [s][4 rows][12] fp16
    __shared__ __align__(16) u16 zin_s[2560];      // 5KB
    __shared__ __align__(16) u16 z1_s[4096];       // 8KB
    __shared__ __align__(16) u16 z2_s[4096];       // 8KB
    __shared__ __align__(16) float r1s[2016];      // 8KB [4][504]
    __shared__ float bfcs[4];

    uint4* W0ro4 = (uint4*)W0ro_s;
    uint4* zin4  = (uint4*)zin_s;
    uint4* z1_4  = (uint4*)z1_s;
    uint4* z2_4  = (uint4*)z2_s;

    // ---- persistent weight fragments -> registers ----
    f16x8 w0a[5], w0b[5];
    f16x8 w1f0[8], w1f1[8], w4a[8], w4b[8], w4c[8];
    #pragma unroll
    for (int s = 0; s < 5; ++s) {
        w0a[s] = bc8_(W0f[((w    ) * 5 + s) * 64 + lane]);
        w0b[s] = bc8_(W0f[((w + 8) * 5 + s) * 64 + lane]);
    }
    #pragma unroll
    for (int s = 0; s < 8; ++s) {
        w1f0[s] = bc8_(W1f[((w     ) * 8 + s) * 64 + lane]);
        w1f1[s] = bc8_(W1f[((w +  8) * 8 + s) * 64 + lane]);
        w4a[s]  = bc8_(W4f[((w     ) * 8 + s) * 64 + lane]);
        w4b[s]  = bc8_(W4f[((w +  8) * 8 + s) * 64 + lane]);
        w4c[s]  = bc8_(W4f[((w + 16) * 8 + s) * 64 + lane]);
    }
    const int u = w * 16 + cl;                     // this thread's unit
    const float bz1a = bb0[u],  bz1b = bb0[128 + u];
    const float bz2a = bb1[u],  bz2b = bb1[128 + u];
    const float bf1r = bff1[u], bf2r = bff2[u];
    const float btsr = bta[u] + btb[u];

    // ---- prologue LDS fills ----
    for (int i = tid; i < 320; i += 512) W0ro4[i] = W0f[5120 + i];   // tile 16
    for (int i = tid; i < 8064; i += 512) {
        int s = i / 48, rem = i - s * 48, r = rem / 12, ii = rem - r * 12;
        xh[i] = f2h_(x1g[((b0 + r) * SS + s) * FF + ii]);
    }
    for (int i = tid; i < 320; i += 512) zin4[i] = make_uint4(0, 0, 0, 0);
    for (int i = tid; i < 512; i += 512) z1_4[i] = make_uint4(0, 0, 0, 0);
    for (int i = tid; i < 512; i += 512) z2_4[i] = make_uint4(0, 0, 0, 0);
    if (tid < 3) bfcs[tid] = bfc[tid];
    __syncthreads();
    if (tid < 48) {                                 // x for s=0, row r -> tile row 4r
        int r = tid / 12, i = tid % 12;
        zin_s[aslot_(r * 4, i)] = xh[tid];
    }
    __syncthreads();

    #pragma unroll 1
    for (int s = 0; s < SS; ++s) {
        // ---- Phase A: GEMM1 z1pre = W0 * [x(s); h(s-1)]; wave 0 also does
        //      the readout MFMA for h(s-1) reusing the same A fragments ----
        f32x4 a1a0 = {0.f,0.f,0.f,0.f}, a1a1 = {0.f,0.f,0.f,0.f};
        f32x4 a1b0 = {0.f,0.f,0.f,0.f}, a1b1 = {0.f,0.f,0.f,0.f};
        f32x4 accr = {0.f,0.f,0.f,0.f};
        #pragma unroll
        for (int ks = 0; ks < 5; ++ks) {
            f16x8 av = bc8_(zin4[ks * 64 + lane]);
            if (ks & 1) { a1a1 = MFMA16(av, w0a[ks], a1a1); a1b1 = MFMA16(av, w0b[ks], a1b1); }
            else        { a1a0 = MFMA16(av, w0a[ks], a1a0); a1b0 = MFMA16(av, w0b[ks], a1b0); }
            if (w == 0) accr = MFMA16(av, bc8_(W0ro4[ks * 64 + lane]), accr);
        }
        if (w == 0 && s > 0 && cl < 3)             // r1 for step s-1, row grp
            r1s[grp * 504 + (s - 1) * 3 + cl] = accr[0] + bfcs[cl];

        // silu + write z1 (1 real row per lane: tile row 4*grp)
        {
            int tr = grp * 4;
            z1_s[aslot_(tr, u)]       = f2h_(siluf_(a1a0[0] + a1a1[0] + bz1a));
            z1_s[aslot_(tr, 128 + u)] = f2h_(siluf_(a1b0[0] + a1b1[0] + bz1b));
        }
        __syncthreads();

        // ---- Phase B: GEMM2 z2pre = W1 * z1 (B in registers) ----
        f32x4 a2a0 = {0.f,0.f,0.f,0.f}, a2a1 = {0.f,0.f,0.f,0.f};
        f32x4 a2b0 = {0.f,0.f,0.f,0.f}, a2b1 = {0.f,0.f,0.f,0.f};
        #pragma unroll
        for (int ks = 0; ks < 8; ++ks) {
            f16x8 av = bc8_(z1_4[ks * 64 + lane]);
            if (ks & 1) { a2a1 = MFMA16(av, w1f0[ks], a2a1); a2b1 = MFMA16(av, w1f1[ks], a2b1); }
            else        { a2a0 = MFMA16(av, w1f0[ks], a2a0); a2b0 = MFMA16(av, w1f1[ks], a2b0); }
        }
        {
            int tr = grp * 4;
            z2_s[aslot_(tr, u)]       = f2h_(siluf_(a2a0[0] + a2a1[0] + bz2a));
            z2_s[aslot_(tr, 128 + u)] = f2h_(siluf_(a2b0[0] + a2b1[0] + bz2b));
        }
        __syncthreads();

        // ---- Phase C: GEMM3 [ff1; ff2; tsum]pre = W4 * z2 (B in registers) ----
        f32x4 c3a0 = {0.f,0.f,0.f,0.f}, c3a1 = {0.f,0.f,0.f,0.f};
        f32x4 c3b0 = {0.f,0.f,0.f,0.f}, c3b1 = {0.f,0.f,0.f,0.f};
        f32x4 c3c0 = {0.f,0.f,0.f,0.f}, c3c1 = {0.f,0.f,0.f,0.f};
        #pragma unroll
        for (int ks = 0; ks < 8; ++ks) {
            f16x8 av = bc8_(z2_4[ks * 64 + lane]);
            if (ks & 1) {
                c3a1 = MFMA16(av, w4a[ks], c3a1);
                c3b1 = MFMA16(av, w4b[ks], c3b1);
                c3c1 = MFMA16(av, w4c[ks], c3c1);
            } else {
                c3a0 = MFMA16(av, w4a[ks], c3a0);
                c3b0 = MFMA16(av, w4b[ks], c3b0);
                c3c0 = MFMA16(av, w4c[ks], c3c0);
            }
        }

        // h update (1 real row per lane)
        {
            float ff1v = tanhf_(c3a0[0] + c3a1[0] + bf1r);
            float ff2v = tanhf_(c3b0[0] + c3b1[0] + bf2r);
            float tv   = sigmoidf_(c3c0[0] + c3c1[0] + btsr);
            float h    = ff1v + tv * (ff2v - ff1v);
            zin_s[aslot_(grp * 4, 12 + u)] = f2h_(h);
        }
        if (tid >= 448 && tid < 496 && s + 1 < SS) {   // x(s+1) copy by wave 7
            int idx = tid - 448;
            int r = idx / 12, i = idx % 12;
            zin_s[aslot_(r * 4, i)] = xh[(s + 1) * 48 + idx];
        }
        __syncthreads();
    }

    // ---- epilogue: readout for s = 167 (h(167) is in zin) ----
    if (w == 0) {
        f32x4 accr = {0.f, 0.f, 0.f, 0.f};
        #pragma unroll
        for (int ks = 0; ks < 5; ++ks)
            accr = MFMA16(bc8_(zin4[ks * 64 + lane]),
                          bc8_(W0ro4[ks * 64 + lane]), accr);
        if (cl < 3)
            r1s[grp * 504 + 167 * 3 + cl] = accr[0] + bfcs[cl];
    }
    __syncthreads();
    for (int idx = tid; idx < 2016; idx += 512) {
        int r = idx / 504, rem = idx - r * 504;
        r1g[(b0 + r) * 504 + rem] = r1s[r * 504 + rem];
    }
}

// ---------------------------------------------------------------------------
// Final fits einsum (x3 folded in):
// out[b,p,c] = sum_s (r1[b,s,c]+x3[b,s,c]) * Wfits[c,p,s] + mean[b,c] + x2[b,p,c]
// ---------------------------------------------------------------------------
__global__ __launch_bounds__(256) void fits_kernel(
    const float* __restrict__ r1, const float* __restrict__ x3,
    const float* __restrict__ Wfits,
    const float* __restrict__ x2, const float* __restrict__ meanbuf,
    float* __restrict__ out)
{
    int bid = blockIdx.x;
    int bt = bid & 7;
    int rest = bid >> 3;
    int c = rest % 3;
    int pt = rest / 3;
    int b0 = bt * 64, p0 = pt * 28;
    __shared__ float rT[168][65];
    __shared__ float wT[28][168];
    int t = threadIdx.x;
    for (int idx = t; idx < 64 * 168; idx += 256) {
        int b = idx / 168, s = idx - b * 168;
        int gi = ((b0 + b) * 168 + s) * 3 + c;
        rT[s][b] = r1[gi] + x3[gi];
    }
    for (int idx = t; idx < 28 * 168; idx += 256) {
        int p = idx / 168, s = idx - p * 168;
        wT[p][s] = Wfits[(c * 168 + p0 + p) * 168 + s];
    }
    __syncthreads();
    int b = t & 63, pq = t >> 6;
    float acc[7] = {0, 0, 0, 0, 0, 0, 0};
    for (int s = 0; s < 168; ++s) {
        float v = rT[s][b];
        #pragma unroll
        for (int j = 0; j < 7; ++j) acc[j] += v * wT[pq * 7 + j][s];
    }
    float mb = meanbuf[(b0 + b) * 12 + c];
    #pragma unroll
    for (int j = 0; j < 7; ++j) {
        int p = p0 + pq * 7 + j;
        int gi = ((b0 + b) * 168 + p) * 3 + c;
        out[gi] = acc[j] + mb + x2[gi];
    }
}

extern "C" void kernel_launch(void* const* d_in, const int* in_sizes, int n_in,
                              void* d_out, int out_size, void* d_ws, size_t ws_size,
                              hipStream_t stream) {
    const float* x    = (const float*)d_in[0];
    const float* c3   = (const float*)d_in[1];
    const float* l3   = (const float*)d_in[2];
    const float* c6   = (const float*)d_in[3];
    const float* l6   = (const float*)d_in[4];
    const float* c12  = (const float*)d_in[5];
    const float* l12  = (const float*)d_in[6];
    const float* c24  = (const float*)d_in[7];
    const float* l24  = (const float*)d_in[8];
    const float* Wb0  = (const float*)d_in[9];
    const float* bb0  = (const float*)d_in[10];
    const float* Wb1  = (const float*)d_in[11];
    const float* bb1  = (const float*)d_in[12];
    const float* Wff1 = (const float*)d_in[13];
    const float* bff1 = (const float*)d_in[14];
    const float* Wff2 = (const float*)d_in[15];
    const float* bff2 = (const float*)d_in[16];
    const float* Wta  = (const float*)d_in[17];
    const float* bta  = (const float*)d_in[18];
    const float* Wtb  = (const float*)d_in[19];
    const float* btb  = (const float*)d_in[20];
    const float* Wfc  = (const float*)d_in[21];
    const float* bfc  = (const float*)d_in[22];
    const float* Wfits= (const float*)d_in[23];

    float* ws      = (float*)d_ws;
    float* meanbuf = ws;                    // 6144
    float* x1      = meanbuf + 6144;        // 1032192
    float* x2      = x1 + 1032192;          // 258048
    float* x3      = x2 + 258048;           // 258048
    float* r1      = x3 + 258048;           // 258048
    u16*   W0f     = (u16*)(r1 + 258048);   // 43520 u16 (16B aligned)
    u16*   W1f     = W0f + 43520;           // 65536 u16
    u16*   W4f     = W1f + 65536;           // 98304 u16
    float* out     = (float*)d_out;

    front_kernel<<<PREP_BLOCKS + SFFA_BLOCKS, 256, 0, stream>>>(
        x, c3, l3, c6, l6, c12, l12, c24, l24,
        Wb0, Wb1, Wff1, Wff2, Wta, Wtb, Wfc,
        W0f, W1f, W4f, meanbuf, x1, x2, x3);
    scan_kernel<<<BB / 4, 512, 0, stream>>>(x1,
                                            (const uint4*)W0f, (const uint4*)W1f, (const uint4*)W4f,
                                            bb0, bb1, bff1, bff2, bta, btb, bfc, r1);
    fits_kernel<<<144, 256, 0, stream>>>(r1, x3, Wfits, x2, meanbuf, out);
}